// Round 1
// baseline (4591.221 us; speedup 1.0000x reference)
//
#include <hip/hip_runtime.h>
#include <hip/hip_bf16.h>
#include <hip/hip_cooperative_groups.h>
#include <math.h>

namespace cg = cooperative_groups;

typedef __bf16 bf16_t;
typedef bf16_t bf16x8 __attribute__((ext_vector_type(8)));
typedef float f32x4 __attribute__((ext_vector_type(4)));

#define T_SEQ 128
#define NB 32
#define NV 32000
#define NE 512
#define NH 1024
#define G4 4096          // 4*NH
#define MROWS 4064       // 127*32
#define MPAD 4096

// ---------------- prep: casts, gather, zeroing ----------------
__global__ void k_prep(const int* __restrict__ idx, const float* __restrict__ emb,
                       const float* __restrict__ W_ih, const float* __restrict__ W_hh,
                       const float* __restrict__ b_ih, const float* __restrict__ b_hh,
                       const float* __restrict__ W_out, const float* __restrict__ h0,
                       bf16_t* __restrict__ W_ih_bf, bf16_t* __restrict__ W_hh_bf,
                       bf16_t* __restrict__ W_out_bf, bf16_t* __restrict__ x_bf,
                       bf16_t* __restrict__ h_all, bf16_t* __restrict__ h0_bf,
                       float* __restrict__ bc, float* __restrict__ rowS,
                       int* __restrict__ tgt) {
  const long nW_ih = 4096L * 512;
  const long nW_hh = 4096L * 1024;
  const long nW_out = 32000L * 1024;
  const long nX = 4096L * 512;
  const long nH0 = 32L * 1024;
  const long nHpad = 32L * 1024;
  const long NTOTAL = nW_ih + nW_hh + nW_out + nX + nH0 + nHpad + 3 * 4096L;
  long stride = (long)gridDim.x * blockDim.x;
  for (long i = (long)blockIdx.x * blockDim.x + threadIdx.x; i < NTOTAL; i += stride) {
    long j = i;
    if (j < nW_ih) { W_ih_bf[j] = (bf16_t)W_ih[j]; continue; }
    j -= nW_ih;
    if (j < nW_hh) { W_hh_bf[j] = (bf16_t)W_hh[j]; continue; }
    j -= nW_hh;
    if (j < nW_out) { W_out_bf[j] = (bf16_t)W_out[j]; continue; }
    j -= nW_out;
    if (j < nX) {
      long m = j >> 9; int e = (int)(j & 511);
      float x = 0.f;
      if (m < MROWS) { x = emb[(long)idx[m] * NE + e]; x = x > 0.f ? x : 0.f; }
      x_bf[j] = (bf16_t)x; continue;
    }
    j -= nX;
    if (j < nH0) { h0_bf[j] = (bf16_t)h0[j]; continue; }
    j -= nH0;
    if (j < nHpad) { h_all[4161536L + j] = (bf16_t)0.f; continue; }  // pad rows 4064..4095
    j -= nHpad;
    if (j < 4096) { bc[j] = b_ih[j] + b_hh[j]; continue; }
    j -= 4096;
    if (j < 4096) { rowS[j] = 0.f; continue; }
    j -= 4096;
    { tgt[j] = (j < MROWS) ? idx[j + NB] : 0; continue; }
  }
}

// ---------------- GEMM1: gates_x = x @ W_ih^T + (b_ih+b_hh), bf16 out ----------------
// C(4096x4096) = A(4096x512) * B(4096x512)^T.  block tile 64x128, 4 waves 2x2.
__global__ __launch_bounds__(256) void k_gemm1(const bf16_t* __restrict__ A,
                                               const bf16_t* __restrict__ B,
                                               const float* __restrict__ bc,
                                               bf16_t* __restrict__ C) {
  const int K = 512;
  int tid = threadIdx.x, wid = tid >> 6, lane = tid & 63;
  int wm = wid & 1, wn = wid >> 1;
  int quad = lane >> 4, l15 = lane & 15;
  int mBase = blockIdx.x * 64, nBase = blockIdx.y * 128;

  const bf16x8* pa0 = (const bf16x8*)(A + (long)(mBase + wm * 32 + l15) * K + quad * 8);
  const bf16x8* pa1 = (const bf16x8*)(A + (long)(mBase + wm * 32 + 16 + l15) * K + quad * 8);
  const bf16x8* pb[4];
#pragma unroll
  for (int j = 0; j < 4; ++j)
    pb[j] = (const bf16x8*)(B + (long)(nBase + wn * 64 + j * 16 + l15) * K + quad * 8);

  f32x4 acc[2][4];
#pragma unroll
  for (int mi = 0; mi < 2; ++mi)
#pragma unroll
    for (int ni = 0; ni < 4; ++ni) acc[mi][ni] = (f32x4){0.f, 0.f, 0.f, 0.f};

  for (int kk = 0; kk < K / 32; ++kk) {
    bf16x8 a0 = pa0[kk * 4], a1 = pa1[kk * 4];
    bf16x8 b0 = pb[0][kk * 4], b1 = pb[1][kk * 4], b2 = pb[2][kk * 4], b3 = pb[3][kk * 4];
    acc[0][0] = __builtin_amdgcn_mfma_f32_16x16x32_bf16(a0, b0, acc[0][0], 0, 0, 0);
    acc[0][1] = __builtin_amdgcn_mfma_f32_16x16x32_bf16(a0, b1, acc[0][1], 0, 0, 0);
    acc[0][2] = __builtin_amdgcn_mfma_f32_16x16x32_bf16(a0, b2, acc[0][2], 0, 0, 0);
    acc[0][3] = __builtin_amdgcn_mfma_f32_16x16x32_bf16(a0, b3, acc[0][3], 0, 0, 0);
    acc[1][0] = __builtin_amdgcn_mfma_f32_16x16x32_bf16(a1, b0, acc[1][0], 0, 0, 0);
    acc[1][1] = __builtin_amdgcn_mfma_f32_16x16x32_bf16(a1, b1, acc[1][1], 0, 0, 0);
    acc[1][2] = __builtin_amdgcn_mfma_f32_16x16x32_bf16(a1, b2, acc[1][2], 0, 0, 0);
    acc[1][3] = __builtin_amdgcn_mfma_f32_16x16x32_bf16(a1, b3, acc[1][3], 0, 0, 0);
  }
#pragma unroll
  for (int ni = 0; ni < 4; ++ni) {
    int col = nBase + wn * 64 + ni * 16 + l15;
    float bcv = bc[col];
#pragma unroll
    for (int mi = 0; mi < 2; ++mi)
#pragma unroll
      for (int r = 0; r < 4; ++r) {
        int row = mBase + wm * 32 + mi * 16 + quad * 4 + r;
        C[(long)row * G4 + col] = (bf16_t)(acc[mi][ni][r] + bcv);
      }
  }
}

// ---------------- cooperative LSTM recurrence ----------------
// 64 blocks x 256 threads; block owns 16 h-units (64 gate rows).
__global__ __launch_bounds__(256) void k_rec(const bf16_t* __restrict__ gates_x,
                                             const bf16_t* __restrict__ W_hh_bf,
                                             const bf16_t* __restrict__ h0_bf,
                                             bf16_t* __restrict__ h_all,
                                             const float* __restrict__ c0) {
  cg::grid_group grid = cg::this_grid();
  int bid = blockIdx.x;
  int tid = threadIdx.x, wid = tid >> 6, lane = tid & 63;
  int mi = wid & 1;       // batch half: rows mi*16..mi*16+15
  int ug = wid >> 1;      // unit subgroup (8 units each)
  int quad = lane >> 4, l15 = lane & 15, l7 = lane & 7;

  int ubase = bid * 16 + ug * 8;
  int uu = ubase + (l15 & 7);
  int row_if = (l15 < 8) ? uu : (1024 + uu);   // cols 0..7 = i rows, 8..15 = f rows
  int row_go = row_if + 2048;                  // cols 0..7 = g rows, 8..15 = o rows
  const bf16x8* pw_if = (const bf16x8*)(W_hh_bf + (long)row_if * NH + quad * 8);
  const bf16x8* pw_go = (const bf16x8*)(W_hh_bf + (long)row_go * NH + quad * 8);

  bool active = (lane & 8) == 0;
  int ub = ubase + l7;       // global h-unit for active lanes
  float cst[4];
#pragma unroll
  for (int r = 0; r < 4; ++r) {
    int b = mi * 16 + quad * 4 + r;
    cst[r] = active ? c0[(long)b * NH + ub] : 0.f;
  }

  for (int t = 0; t < T_SEQ - 1; ++t) {
    const bf16_t* hp = (t == 0) ? h0_bf : (h_all + (long)(t - 1) * NB * NH);
    const bf16x8* pa = (const bf16x8*)(hp + (long)(mi * 16 + l15) * NH + quad * 8);
    f32x4 aif = (f32x4){0.f, 0.f, 0.f, 0.f};
    f32x4 ago = (f32x4){0.f, 0.f, 0.f, 0.f};
#pragma unroll 4
    for (int kk = 0; kk < NH / 32; ++kk) {
      bf16x8 a = pa[kk * 4];
      bf16x8 wif = pw_if[kk * 4];
      bf16x8 wgo = pw_go[kk * 4];
      aif = __builtin_amdgcn_mfma_f32_16x16x32_bf16(a, wif, aif, 0, 0, 0);
      ago = __builtin_amdgcn_mfma_f32_16x16x32_bf16(a, wgo, ago, 0, 0, 0);
    }
    int mrow0 = t * NB + mi * 16 + quad * 4;
#pragma unroll
    for (int r = 0; r < 4; ++r) {
      aif[r] += (float)gates_x[(long)(mrow0 + r) * G4 + row_if];
      ago[r] += (float)gates_x[(long)(mrow0 + r) * G4 + row_go];
    }
#pragma unroll
    for (int r = 0; r < 4; ++r) {
      float iv = aif[r];
      float fv = __shfl_xor(aif[r], 8);
      float gv = ago[r];
      float ov = __shfl_xor(ago[r], 8);
      if (active) {
        float si = 1.f / (1.f + __expf(-iv));
        float sf = 1.f / (1.f + __expf(-fv));
        float so = 1.f / (1.f + __expf(-ov));
        float cn = sf * cst[r] + si * tanhf(gv);
        cst[r] = cn;
        float hn = so * tanhf(cn);
        h_all[(long)(t * NB + mi * 16 + quad * 4 + r) * NH + ub] = (bf16_t)hn;
      }
    }
    grid.sync();
  }
}

// ---------------- GEMM2: logits + exp-rowsum epilogue ----------------
// C(4096x32000) = h_all(4096x1024) @ W_out^T; rowS[m] += sum_n exp(C[m][n]+b_out[n])
__global__ __launch_bounds__(256) void k_gemm2(const bf16_t* __restrict__ A,
                                               const bf16_t* __restrict__ B,
                                               const float* __restrict__ b_out,
                                               float* __restrict__ rowS) {
  const int K = 1024;
  int tid = threadIdx.x, wid = tid >> 6, lane = tid & 63;
  int wm = wid & 1, wn = wid >> 1;
  int quad = lane >> 4, l15 = lane & 15;
  int mBase = blockIdx.x * 64, nBase = blockIdx.y * 128;

  const bf16x8* pa0 = (const bf16x8*)(A + (long)(mBase + wm * 32 + l15) * K + quad * 8);
  const bf16x8* pa1 = (const bf16x8*)(A + (long)(mBase + wm * 32 + 16 + l15) * K + quad * 8);
  const bf16x8* pb[4];
#pragma unroll
  for (int j = 0; j < 4; ++j)
    pb[j] = (const bf16x8*)(B + (long)(nBase + wn * 64 + j * 16 + l15) * K + quad * 8);

  f32x4 acc[2][4];
#pragma unroll
  for (int mi = 0; mi < 2; ++mi)
#pragma unroll
    for (int ni = 0; ni < 4; ++ni) acc[mi][ni] = (f32x4){0.f, 0.f, 0.f, 0.f};

  for (int kk = 0; kk < K / 32; ++kk) {
    bf16x8 a0 = pa0[kk * 4], a1 = pa1[kk * 4];
    bf16x8 b0 = pb[0][kk * 4], b1 = pb[1][kk * 4], b2 = pb[2][kk * 4], b3 = pb[3][kk * 4];
    acc[0][0] = __builtin_amdgcn_mfma_f32_16x16x32_bf16(a0, b0, acc[0][0], 0, 0, 0);
    acc[0][1] = __builtin_amdgcn_mfma_f32_16x16x32_bf16(a0, b1, acc[0][1], 0, 0, 0);
    acc[0][2] = __builtin_amdgcn_mfma_f32_16x16x32_bf16(a0, b2, acc[0][2], 0, 0, 0);
    acc[0][3] = __builtin_amdgcn_mfma_f32_16x16x32_bf16(a0, b3, acc[0][3], 0, 0, 0);
    acc[1][0] = __builtin_amdgcn_mfma_f32_16x16x32_bf16(a1, b0, acc[1][0], 0, 0, 0);
    acc[1][1] = __builtin_amdgcn_mfma_f32_16x16x32_bf16(a1, b1, acc[1][1], 0, 0, 0);
    acc[1][2] = __builtin_amdgcn_mfma_f32_16x16x32_bf16(a1, b2, acc[1][2], 0, 0, 0);
    acc[1][3] = __builtin_amdgcn_mfma_f32_16x16x32_bf16(a1, b3, acc[1][3], 0, 0, 0);
  }

#pragma unroll
  for (int mi = 0; mi < 2; ++mi) {
    float rs[4] = {0.f, 0.f, 0.f, 0.f};
#pragma unroll
    for (int ni = 0; ni < 4; ++ni) {
      int col = nBase + wn * 64 + ni * 16 + l15;
      float bb = b_out[col];
#pragma unroll
      for (int r = 0; r < 4; ++r) rs[r] += __expf(acc[mi][ni][r] + bb);
    }
#pragma unroll
    for (int r = 0; r < 4; ++r) {
#pragma unroll
      for (int s = 1; s < 16; s <<= 1) rs[r] += __shfl_xor(rs[r], s);
      if (l15 == 0) {
        int row = mBase + wm * 32 + mi * 16 + quad * 4 + r;
        if (row < MROWS) atomicAdd(&rowS[row], rs[r]);
      }
    }
  }
}

// ---------------- target logits: one wave per (t,b) row ----------------
__global__ __launch_bounds__(256) void k_tgt(const bf16_t* __restrict__ h_all,
                                             const bf16_t* __restrict__ W_out_bf,
                                             const float* __restrict__ b_out,
                                             const int* __restrict__ tgt,
                                             float* __restrict__ tgt_logit) {
  int gw = (int)((blockIdx.x * blockDim.x + threadIdx.x) >> 6);
  int lane = threadIdx.x & 63;
  if (gw >= MROWS) return;
  int v = tgt[gw];
  const bf16x8* ph = (const bf16x8*)(h_all + (long)gw * NH + lane * 16);
  const bf16x8* pw = (const bf16x8*)(W_out_bf + (long)v * NH + lane * 16);
  float acc = 0.f;
#pragma unroll
  for (int j = 0; j < 2; ++j) {
    bf16x8 h8 = ph[j], w8 = pw[j];
#pragma unroll
    for (int q = 0; q < 8; ++q) acc += (float)h8[q] * (float)w8[q];
  }
#pragma unroll
  for (int s = 1; s < 64; s <<= 1) acc += __shfl_xor(acc, s);
  if (lane == 0) tgt_logit[gw] = acc + b_out[v];
}

// ---------------- final loss reduction ----------------
__global__ __launch_bounds__(256) void k_loss(const float* __restrict__ rowS,
                                              const float* __restrict__ tl,
                                              const int* __restrict__ tgt,
                                              float* __restrict__ out) {
  __shared__ float sm[256];
  float s = 0.f;
  for (int i = threadIdx.x; i < MROWS; i += 256)
    if (tgt[i] != 0) s += logf(rowS[i]) - tl[i];
  sm[threadIdx.x] = s;
  __syncthreads();
  for (int off = 128; off > 0; off >>= 1) {
    if (threadIdx.x < off) sm[threadIdx.x] += sm[threadIdx.x + off];
    __syncthreads();
  }
  if (threadIdx.x == 0) out[0] = sm[0];
}

extern "C" void kernel_launch(void* const* d_in, const int* in_sizes, int n_in,
                              void* d_out, int out_size, void* d_ws, size_t ws_size,
                              hipStream_t stream) {
  const int* idx = (const int*)d_in[0];
  const float* emb = (const float*)d_in[1];
  const float* W_ih = (const float*)d_in[2];
  const float* W_hh = (const float*)d_in[3];
  const float* b_ih = (const float*)d_in[4];
  const float* b_hh = (const float*)d_in[5];
  const float* W_out = (const float*)d_in[6];
  const float* b_out = (const float*)d_in[7];
  const float* h0 = (const float*)d_in[8];
  const float* c0 = (const float*)d_in[9];

  char* ws = (char*)d_ws;
  bf16_t* W_ih_bf = (bf16_t*)ws;            ws += 4096L * 512 * 2;
  bf16_t* W_hh_bf = (bf16_t*)ws;            ws += 4096L * 1024 * 2;
  bf16_t* W_out_bf = (bf16_t*)ws;           ws += 32000L * 1024 * 2;
  bf16_t* x_bf = (bf16_t*)ws;               ws += 4096L * 512 * 2;
  bf16_t* gates_x = (bf16_t*)ws;            ws += 4096L * 4096 * 2;
  bf16_t* h_all = (bf16_t*)ws;              ws += 4096L * 1024 * 2;
  bf16_t* h0_bf = (bf16_t*)ws;              ws += 32L * 1024 * 2;
  float* bc = (float*)ws;                   ws += 4096L * 4;
  float* rowS = (float*)ws;                 ws += 4096L * 4;
  float* tgt_logit = (float*)ws;            ws += 4096L * 4;
  int* tgt = (int*)ws;                      ws += 4096L * 4;

  k_prep<<<4096, 256, 0, stream>>>(idx, emb, W_ih, W_hh, b_ih, b_hh, W_out, h0,
                                   W_ih_bf, W_hh_bf, W_out_bf, x_bf, h_all, h0_bf,
                                   bc, rowS, tgt);

  k_gemm1<<<dim3(64, 32), 256, 0, stream>>>(x_bf, W_ih_bf, bc, gates_x);

  {
    void* args[] = {(void*)&gates_x, (void*)&W_hh_bf, (void*)&h0_bf, (void*)&h_all, (void*)&c0};
    hipLaunchCooperativeKernel((void*)k_rec, dim3(64), dim3(256), args, 0, stream);
  }

  k_gemm2<<<dim3(64, 250), 256, 0, stream>>>(h_all, W_out_bf, b_out, rowS);

  k_tgt<<<1016, 256, 0, stream>>>(h_all, W_out_bf, b_out, tgt, tgt_logit);

  k_loss<<<1, 256, 0, stream>>>(rowS, tgt_logit, tgt, (float*)d_out);
}